// Round 1
// baseline (285.791 us; speedup 1.0000x reference)
//
#include <hip/hip_runtime.h>

#define DTC 0.2f
#define EPSC 1e-8f

// mono(x) = -(SufW[i]*x + SufB[i]) + bo,  i = #{knots <= x}  (5-step search)
// kn layout: [0..31] sorted knots, [32..64] SufW (SufW[32]=0), [65..97] SufB
__device__ __forceinline__ float mono_eval(const float* __restrict__ kn, float x) {
    int i = (kn[15] <= x) ? 16 : 0;
    i += (kn[i + 7] <= x) ? 8 : 0;
    i += (kn[i + 3] <= x) ? 4 : 0;
    i += (kn[i + 1] <= x) ? 2 : 0;
    i += (kn[i] <= x) ? 1 : 0;
    return -fmaf(kn[32 + i], x, kn[65 + i]);
}

// ---------------------------------------------------------------------------
// Fused kernel: per-block replicated pre-work (knot sort + suffix sums + dlf)
// into shared memory, then the 8-lanes-per-row main phase. NO d_ws usage —
// the 570 MB workspace re-poison fills (3x82us/iter) leave the timed window.
// ---------------------------------------------------------------------------
__global__ __launch_bounds__(256) void sfm_fused(
    const float* __restrict__ ego, const float* __restrict__ nei,
    const float* __restrict__ border, const float* __restrict__ adp,
    const float* __restrict__ eang,
    const float* __restrict__ an_wi, const float* __restrict__ an_bi,
    const float* __restrict__ an_wo, const float* __restrict__ an_bo,
    const float* __restrict__ rn_wi, const float* __restrict__ rn_bi,
    const float* __restrict__ rn_wo, const float* __restrict__ rn_bo,
    const float* __restrict__ rb_wi, const float* __restrict__ rb_bi,
    const float* __restrict__ rb_wo, const float* __restrict__ rb_bo,
    const float* __restrict__ dl_wi, const float* __restrict__ dl_bi,
    const float* __restrict__ dl_wo, const float* __restrict__ dl_bo,
    float* __restrict__ out, int Bn)
{
    // sw layout: [0..7] dlf | an@16, rn@128, rb@240 (knots/SufW/SufB) |
    //            [352..359] an_bo, rn_bo, rb_bo, adp0, adp1, ang, border0, border3
    __shared__ float sw[360];
    __shared__ float tk[96], w1[96], w2[96], sk[96], s1[96], s2[96];

    int t = threadIdx.x;
    int l = t & 7;                                  // record index within row
    long long row = (long long)blockIdx.x * 32 + (t >> 3);
    long long prow = (row < Bn) ? row : (long long)(Bn - 1);

    // --- main-phase prefetch: issue the HBM loads BEFORE the pre-work so
    //     their ~900-cycle latency hides under the replicated computation ---
    const float* nr = nei + prow * 136 + l * 17 + 2;
    float nx = nr[0], ny = nr[1], vx = nr[2], vy = nr[3];
    float egv = 0.f;
    if (l < 6) egv = ego[prow * 51 + 34 + l];

    // --- pre-work, replicated per block (all inputs L2-resident) ---
    if (t < 96) {
        int f = t >> 5, k = t & 31;
        const float* wip = (f == 0) ? an_wi : ((f == 1) ? rn_wi : rb_wi);
        const float* bip = (f == 0) ? an_bi : ((f == 1) ? rn_bi : rb_bi);
        const float* wop = (f == 0) ? an_wo : ((f == 1) ? rn_wo : rb_wo);
        float wi = wip[k], bi = bip[k], wo = wop[k];
        tk[t] = -bi / wi;
        w1[t] = wi * wo;
        w2[t] = wo * bi;
    }
    if (t >= 96 && t < 104) {                       // dlf[j], bo folded in
        int j = t - 96;
        const float* base = ego + 51;               // ego[1, :, :]
        float idv = base[2 * 17 + 8 + j];
        float dur = 0.f;
        for (int tt = 0; tt < 3; ++tt) {
            bool fo = false;
            for (int m = 0; m < 8; ++m) fo = fo || (idv == base[tt * 17 + 8 + m]);
            dur += fo ? 1.f : 0.f;
        }
        float acc = 0.f;
#pragma unroll
        for (int k = 0; k < 32; ++k)
            acc = fmaf(dl_wo[k], fmaxf(0.f, -fmaf(dl_wi[k], dur, dl_bi[k])), acc);
        sw[j] = acc + dl_bo[0];
    }
    if (t == 104) sw[352] = an_bo[0];
    if (t == 105) sw[353] = rn_bo[0];
    if (t == 106) sw[354] = rb_bo[0];
    if (t == 107) sw[355] = adp[0];
    if (t == 108) sw[356] = adp[1];
    if (t == 109) sw[357] = eang[0];
    if (t == 110) sw[358] = border[0];
    if (t == 111) sw[359] = border[3];
    __syncthreads();

    if (t < 96) {                                   // rank-sort the knots
        int k = t & 31, b = t & ~31;
        float my = tk[t];
        int rank = 0;
#pragma unroll
        for (int m = 0; m < 32; ++m) {              // broadcast LDS reads
            float o = tk[b + m];
            rank += (o < my || (o == my && m < k)) ? 1 : 0;
        }
        sk[b + rank] = my;
        s1[b + rank] = w1[t];
        s2[b + rank] = w2[t];
    }
    __syncthreads();

    if (t < 96) {                                   // suffix sums (same order as ref)
        int f = t >> 5, p = t & 31, b = t & ~31;
        float sw_ = 0.f, sb_ = 0.f;
#pragma unroll
        for (int m = 0; m < 32; ++m) {              // broadcast LDS reads, predicated
            float a = s1[b + m], c = s2[b + m];
            if (m >= p) { sw_ += a; sb_ += c; }
        }
        int base = 16 + f * 112;
        sw[base + p]      = sk[b + p];
        sw[base + 32 + p] = sw_;
        sw[base + 65 + p] = sb_;
        if (p == 0) { sw[base + 64] = 0.f; sw[base + 97] = 0.f; }
    }
    __syncthreads();

    // --- main phase: 8 lanes per row, 32 rows per block ---
    if (row < Bn) {
        int lb = (t & 63) & ~7;
        float g0 = __shfl(egv, lb + 0, 64);
        float g1 = __shfl(egv, lb + 1, 64);
        float g2 = __shfl(egv, lb + 2, 64);
        float g3 = __shfl(egv, lb + 3, 64);
        float g4 = __shfl(egv, lb + 4, 64);
        float g5 = __shfl(egv, lb + 5, 64);

        float Rx = nx - g2, Ry = ny - g3;
        float rr = sqrtf(Rx * Rx + Ry * Ry);
        float ax = fmaf(vx, DTC, Rx), ay = fmaf(vy, DTC, Ry);
        float wx = vx * DTC, wy = vy * DTC;
        float bb = sqrtf(rr + ax * ax + ay * ay - wx * wx - wy * wy) * 0.5f;

        float an_bo_v = sw[352], rn_bo_v = sw[353], rb_bo_v = sw[354];
        float p0 = sw[355], p1 = sw[356], ang = sw[357];
        float rb0 = g3 - sw[358], rb1 = g3 - sw[359];
        float rbn0 = fabsf(rb0), rbn1 = fabsf(rb1);

        float fA = mono_eval(sw + 16, rr) + an_bo_v;
        float fR = mono_eval(sw + 128, bb) + rn_bo_v;
        float xb = (l == 1) ? rbn1 : rbn0;
        float vB = 0.f;
        if (l < 2) vB = mono_eval(sw + 240, xb) + rb_bo_v;
        float vB0 = __shfl(vB, lb + 0, 64);
        float vB1 = __shfl(vB, lb + 1, 64);

        // e = normalize(ego_last[4:6])
        float elen = sqrtf(g4 * g4 + g5 * g5);
        float ex = g4 / elen, ey = g5 / elen;
        float na = fmaxf(sqrtf(ex * ex + ey * ey), EPSC);

        float axs = 0.f, ays = 0.f;
#define CLAMP_ADD(VX, VY)                                                   \
        {                                                                   \
            float _vx = (VX), _vy = (VY);                                   \
            float _nv = fmaxf(sqrtf(_vx * _vx + _vy * _vy), EPSC);          \
            float _c = (ex * _vx + ey * _vy) / (na * _nv);                  \
            if (fabsf(_c) > ang) { axs += _vx; ays += _vy; }                \
        }

        float mfx = (nx == 0.f) ? 0.f : 1.f;
        float mfy = (ny == 0.f) ? 0.f : 1.f;

        { // f_attr for this record
            float coef = fA / rr * sw[l];           // dlf factor
            CLAMP_ADD(coef * Rx * mfx, coef * Ry * mfy);
        }
        { // f_repu for this record
            float coef = fR / rr;
            CLAMP_ADD(coef * Rx * mfx, coef * Ry * mfy);
        }

        // reduce axs/ays over the 8 lanes of the row
#pragma unroll
        for (int m = 1; m < 8; m <<= 1) {
            axs += __shfl_xor(axs, m, 64);
            ays += __shfl_xor(ays, m, 64);
        }

        if (l == 0) {
            // f_dest
            float dvn = sqrtf(g3 * g3 + g4 * g4);
            CLAMP_ADD((p1 * dvn - g3) / p0, -g4 / p0);
            // f_bor: (0, mono_rb(|rbv|) * sign(rbv)) for the two borders
            CLAMP_ADD(0.f, vB0 * (rb0 / rbn0));
            CLAMP_ADD(0.f, vB1 * (rb1 / rbn1));

            float vxo = fmaf(axs, DTC, g2);
            float vyo = fmaf(ays, DTC, g3);
            float* op = out + row * 6;
            op[0] = fmaf(vxo, DTC, g0);
            op[1] = fmaf(vyo, DTC, g1);
            op[2] = vxo; op[3] = vyo;
            op[4] = axs; op[5] = ays;
        }
#undef CLAMP_ADD
    }
}

extern "C" void kernel_launch(void* const* d_in, const int* in_sizes, int n_in,
                              void* d_out, int out_size, void* d_ws, size_t ws_size,
                              hipStream_t stream) {
    const float* ego    = (const float*)d_in[0];
    const float* nei    = (const float*)d_in[1];
    const float* border = (const float*)d_in[2];
    const float* adp    = (const float*)d_in[3];
    const float* eang   = (const float*)d_in[4];
    const float* an_wi  = (const float*)d_in[5];
    const float* an_bi  = (const float*)d_in[6];
    const float* an_wo  = (const float*)d_in[7];
    const float* an_bo  = (const float*)d_in[8];
    const float* rn_wi  = (const float*)d_in[9];
    const float* rn_bi  = (const float*)d_in[10];
    const float* rn_wo  = (const float*)d_in[11];
    const float* rn_bo  = (const float*)d_in[12];
    const float* rb_wi  = (const float*)d_in[13];
    const float* rb_bi  = (const float*)d_in[14];
    const float* rb_wo  = (const float*)d_in[15];
    const float* rb_bo  = (const float*)d_in[16];
    const float* dl_wi  = (const float*)d_in[17];
    const float* dl_bi  = (const float*)d_in[18];
    const float* dl_wo  = (const float*)d_in[19];
    const float* dl_bo  = (const float*)d_in[20];
    float* out = (float*)d_out;
    (void)d_ws; (void)ws_size;                      // deliberately unused

    int Bn = in_sizes[0] / (3 * 17);
    int grid = (Bn + 31) / 32;
    sfm_fused<<<grid, 256, 0, stream>>>(ego, nei, border, adp, eang,
                                        an_wi, an_bi, an_wo, an_bo,
                                        rn_wi, rn_bi, rn_wo, rn_bo,
                                        rb_wi, rb_bi, rb_wo, rb_bo,
                                        dl_wi, dl_bi, dl_wo, dl_bo,
                                        out, Bn);
}

// Round 2
// 282.432 us; speedup vs baseline: 1.0119x; 1.0119x over previous
//
#include <hip/hip_runtime.h>

#define DTC 0.2f
#define EPSC 1e-8f

// mono(x) = -(SufW[i]*x + SufB[i]) + bo,  i = #{knots <= x}  (5-step search)
// kn layout: [0..31] sorted knots, [32..64] SufW (SufW[32]=0), [65..97] SufB
__device__ __forceinline__ float mono_eval(const float* __restrict__ kn, float x) {
    int i = (kn[15] <= x) ? 16 : 0;
    i += (kn[i + 7] <= x) ? 8 : 0;
    i += (kn[i + 3] <= x) ? 4 : 0;
    i += (kn[i + 1] <= x) ? 2 : 0;
    i += (kn[i] <= x) ? 1 : 0;
    return -fmaf(kn[32 + i], x, kn[65 + i]);
}

// ---------------------------------------------------------------------------
// Grid-stride fused kernel: prework ONCE per block (2048 blocks = 8/CU), then
// a 2-stage register pipeline over row-groups: issue group g+1's global loads
// before computing group g, so HBM latency hides under ~1000 cyc of compute.
// Ego fields loaded directly per-lane (no broadcast shuffles after waitcnt).
// ---------------------------------------------------------------------------
__global__ __launch_bounds__(256) void sfm_fused(
    const float* __restrict__ ego, const float* __restrict__ nei,
    const float* __restrict__ border, const float* __restrict__ adp,
    const float* __restrict__ eang,
    const float* __restrict__ an_wi, const float* __restrict__ an_bi,
    const float* __restrict__ an_wo, const float* __restrict__ an_bo,
    const float* __restrict__ rn_wi, const float* __restrict__ rn_bi,
    const float* __restrict__ rn_wo, const float* __restrict__ rn_bo,
    const float* __restrict__ rb_wi, const float* __restrict__ rb_bi,
    const float* __restrict__ rb_wo, const float* __restrict__ rb_bo,
    const float* __restrict__ dl_wi, const float* __restrict__ dl_bi,
    const float* __restrict__ dl_wo, const float* __restrict__ dl_bo,
    float* __restrict__ out, int Bn, int nGroups)
{
    // sw layout: [0..7] dlf | an@16, rn@128, rb@240 (knots/SufW/SufB) |
    //            [352..359] an_bo, rn_bo, rb_bo, adp0, adp1, ang, border0, border3
    __shared__ float sw[360];
    __shared__ float tk[96], w1[96], w2[96], sk[96], s1[96], s2[96];

    int t = threadIdx.x;

    // --- pre-work, once per block (all inputs L2-resident after block 0) ---
    if (t < 96) {
        int f = t >> 5, k = t & 31;
        const float* wip = (f == 0) ? an_wi : ((f == 1) ? rn_wi : rb_wi);
        const float* bip = (f == 0) ? an_bi : ((f == 1) ? rn_bi : rb_bi);
        const float* wop = (f == 0) ? an_wo : ((f == 1) ? rn_wo : rb_wo);
        float wi = wip[k], bi = bip[k], wo = wop[k];
        tk[t] = -bi / wi;
        w1[t] = wi * wo;
        w2[t] = wo * bi;
    }
    if (t >= 96 && t < 104) {                       // dlf[j], bo folded in
        int j = t - 96;
        const float* base = ego + 51;               // ego[1, :, :]
        float idv = base[2 * 17 + 8 + j];
        float dur = 0.f;
        for (int tt = 0; tt < 3; ++tt) {
            bool fo = false;
            for (int m = 0; m < 8; ++m) fo = fo || (idv == base[tt * 17 + 8 + m]);
            dur += fo ? 1.f : 0.f;
        }
        float acc = 0.f;
#pragma unroll
        for (int k = 0; k < 32; ++k)
            acc = fmaf(dl_wo[k], fmaxf(0.f, -fmaf(dl_wi[k], dur, dl_bi[k])), acc);
        sw[j] = acc + dl_bo[0];
    }
    if (t == 104) sw[352] = an_bo[0];
    if (t == 105) sw[353] = rn_bo[0];
    if (t == 106) sw[354] = rb_bo[0];
    if (t == 107) sw[355] = adp[0];
    if (t == 108) sw[356] = adp[1];
    if (t == 109) sw[357] = eang[0];
    if (t == 110) sw[358] = border[0];
    if (t == 111) sw[359] = border[3];
    __syncthreads();

    if (t < 96) {                                   // rank-sort the knots
        int k = t & 31, b = t & ~31;
        float my = tk[t];
        int rank = 0;
#pragma unroll
        for (int m = 0; m < 32; ++m) {
            float o = tk[b + m];
            rank += (o < my || (o == my && m < k)) ? 1 : 0;
        }
        sk[b + rank] = my;
        s1[b + rank] = w1[t];
        s2[b + rank] = w2[t];
    }
    __syncthreads();

    if (t < 96) {                                   // suffix sums (same order as ref)
        int f = t >> 5, p = t & 31, b = t & ~31;
        float sw_ = 0.f, sb_ = 0.f;
#pragma unroll
        for (int m = 0; m < 32; ++m) {
            float a = s1[b + m], c = s2[b + m];
            if (m >= p) { sw_ += a; sb_ += c; }
        }
        int base = 16 + f * 112;
        sw[base + p]      = sk[b + p];
        sw[base + 32 + p] = sw_;
        sw[base + 65 + p] = sb_;
        if (p == 0) { sw[base + 64] = 0.f; sw[base + 97] = 0.f; }
    }
    __syncthreads();

    const int l = t & 7;                            // record index within row
    const int sub = t >> 3;                         // row within group (0..31)
    const int lb = (t & 63) & ~7;                   // base lane of this row

    // hoist all uniform LDS scalars out of the loop
    const float an_bo_v = sw[352], rn_bo_v = sw[353], rb_bo_v = sw[354];
    const float p0 = sw[355], p1 = sw[356], ang = sw[357];
    const float bor0 = sw[358], bor3 = sw[359];
    const float dlf = sw[l];

    long long grp = blockIdx.x;
    const long long gstride = gridDim.x;
    if (grp >= nGroups) return;

    // ---- pipeline stage 0: load first group ----
    float nx, ny, vx, vy, g0, g1, g2, g3, g4, g5;
    {
        long long row = grp * 32 + sub;
        long long prow = (row < Bn) ? row : (long long)(Bn - 1);
        const float* nr = nei + prow * 136 + l * 17 + 2;
        nx = nr[0]; ny = nr[1]; vx = nr[2]; vy = nr[3];
        const float* er = ego + prow * 51 + 34;
        g0 = er[0]; g1 = er[1]; g2 = er[2]; g3 = er[3]; g4 = er[4]; g5 = er[5];
    }

    for (;;) {
        // ---- issue NEXT group's loads before computing current ----
        const long long ngrp = grp + gstride;
        const bool more = (ngrp < nGroups);
        float nx2, ny2, vx2, vy2, h0, h1, h2, h3, h4, h5;
        {
            long long row = more ? (ngrp * 32 + sub) : 0;
            long long prow = (row < Bn) ? row : (long long)(Bn - 1);
            const float* nr = nei + prow * 136 + l * 17 + 2;
            nx2 = nr[0]; ny2 = nr[1]; vx2 = nr[2]; vy2 = nr[3];
            const float* er = ego + prow * 51 + 34;
            h0 = er[0]; h1 = er[1]; h2 = er[2]; h3 = er[3]; h4 = er[4]; h5 = er[5];
        }

        // ---- compute current group (identical formulas/order to r1) ----
        long long row = grp * 32 + sub;
        if (row < Bn) {
            float Rx = nx - g2, Ry = ny - g3;
            float rr = sqrtf(Rx * Rx + Ry * Ry);
            float axq = fmaf(vx, DTC, Rx), ayq = fmaf(vy, DTC, Ry);
            float wxq = vx * DTC, wyq = vy * DTC;
            float bb = sqrtf(rr + axq * axq + ayq * ayq - wxq * wxq - wyq * wyq) * 0.5f;

            float rb0 = g3 - bor0, rb1 = g3 - bor3;
            float rbn0 = fabsf(rb0), rbn1 = fabsf(rb1);

            float fA = mono_eval(sw + 16, rr) + an_bo_v;
            float fR = mono_eval(sw + 128, bb) + rn_bo_v;
            float xb = (l == 1) ? rbn1 : rbn0;
            float vB = 0.f;
            if (l < 2) vB = mono_eval(sw + 240, xb) + rb_bo_v;
            float vB0 = __shfl(vB, lb + 0, 64);
            float vB1 = __shfl(vB, lb + 1, 64);

            // e = normalize(ego_last[4:6])
            float elen = sqrtf(g4 * g4 + g5 * g5);
            float ex = g4 / elen, ey = g5 / elen;
            float na = fmaxf(sqrtf(ex * ex + ey * ey), EPSC);

            float axs = 0.f, ays = 0.f;
#define CLAMP_ADD(VX, VY)                                                   \
            {                                                               \
                float _vx = (VX), _vy = (VY);                               \
                float _nv = fmaxf(sqrtf(_vx * _vx + _vy * _vy), EPSC);      \
                float _c = (ex * _vx + ey * _vy) / (na * _nv);              \
                if (fabsf(_c) > ang) { axs += _vx; ays += _vy; }            \
            }

            float mfx = (nx == 0.f) ? 0.f : 1.f;
            float mfy = (ny == 0.f) ? 0.f : 1.f;

            { // f_attr for this record
                float coef = fA / rr * dlf;
                CLAMP_ADD(coef * Rx * mfx, coef * Ry * mfy);
            }
            { // f_repu for this record
                float coef = fR / rr;
                CLAMP_ADD(coef * Rx * mfx, coef * Ry * mfy);
            }

            // reduce axs/ays over the 8 lanes of the row
#pragma unroll
            for (int m = 1; m < 8; m <<= 1) {
                axs += __shfl_xor(axs, m, 64);
                ays += __shfl_xor(ays, m, 64);
            }

            if (l == 0) {
                // f_dest
                float dvn = sqrtf(g3 * g3 + g4 * g4);
                CLAMP_ADD((p1 * dvn - g3) / p0, -g4 / p0);
                // f_bor: (0, mono_rb(|rbv|) * sign(rbv)) for the two borders
                CLAMP_ADD(0.f, vB0 * (rb0 / rbn0));
                CLAMP_ADD(0.f, vB1 * (rb1 / rbn1));

                float vxo = fmaf(axs, DTC, g2);
                float vyo = fmaf(ays, DTC, g3);
                float* op = out + row * 6;
                op[0] = fmaf(vxo, DTC, g0);
                op[1] = fmaf(vyo, DTC, g1);
                op[2] = vxo; op[3] = vyo;
                op[4] = axs; op[5] = ays;
            }
#undef CLAMP_ADD
        }

        if (!more) break;
        grp = ngrp;
        nx = nx2; ny = ny2; vx = vx2; vy = vy2;
        g0 = h0; g1 = h1; g2 = h2; g3 = h3; g4 = h4; g5 = h5;
    }
}

extern "C" void kernel_launch(void* const* d_in, const int* in_sizes, int n_in,
                              void* d_out, int out_size, void* d_ws, size_t ws_size,
                              hipStream_t stream) {
    const float* ego    = (const float*)d_in[0];
    const float* nei    = (const float*)d_in[1];
    const float* border = (const float*)d_in[2];
    const float* adp    = (const float*)d_in[3];
    const float* eang   = (const float*)d_in[4];
    const float* an_wi  = (const float*)d_in[5];
    const float* an_bi  = (const float*)d_in[6];
    const float* an_wo  = (const float*)d_in[7];
    const float* an_bo  = (const float*)d_in[8];
    const float* rn_wi  = (const float*)d_in[9];
    const float* rn_bi  = (const float*)d_in[10];
    const float* rn_wo  = (const float*)d_in[11];
    const float* rn_bo  = (const float*)d_in[12];
    const float* rb_wi  = (const float*)d_in[13];
    const float* rb_bi  = (const float*)d_in[14];
    const float* rb_wo  = (const float*)d_in[15];
    const float* rb_bo  = (const float*)d_in[16];
    const float* dl_wi  = (const float*)d_in[17];
    const float* dl_bi  = (const float*)d_in[18];
    const float* dl_wo  = (const float*)d_in[19];
    const float* dl_bo  = (const float*)d_in[20];
    float* out = (float*)d_out;
    (void)d_ws; (void)ws_size;                      // deliberately unused

    int Bn = in_sizes[0] / (3 * 17);
    int nGroups = (Bn + 31) / 32;
    int grid = (nGroups < 2048) ? nGroups : 2048;   // 8 blocks/CU, grid-stride
    sfm_fused<<<grid, 256, 0, stream>>>(ego, nei, border, adp, eang,
                                        an_wi, an_bi, an_wo, an_bo,
                                        rn_wi, rn_bi, rn_wo, rn_bo,
                                        rb_wi, rb_bi, rb_wo, rb_bo,
                                        dl_wi, dl_bi, dl_wo, dl_bo,
                                        out, Bn, nGroups);
}

// Round 4
// 278.650 us; speedup vs baseline: 1.0256x; 1.0136x over previous
//
#include <hip/hip_runtime.h>

#define DTC 0.2f
#define EPSC 1e-8f

// mono(x) = -(SufW[i]*x + SufB[i]) + bo,  i = #{knots <= x}  (5-step search)
// kn layout: [0..31] sorted knots, [32..64] SufW (SufW[32]=0), [65..97] SufB
__device__ __forceinline__ float mono_eval(const float* __restrict__ kn, float x) {
    int i = (kn[15] <= x) ? 16 : 0;
    i += (kn[i + 7] <= x) ? 8 : 0;
    i += (kn[i + 3] <= x) ? 4 : 0;
    i += (kn[i + 1] <= x) ? 2 : 0;
    i += (kn[i] <= x) ? 1 : 0;
    return -fmaf(kn[32 + i], x, kn[65 + i]);
}

// ---------------------------------------------------------------------------
// One thread = one row. 16 independent mono chains/thread (ILP hides LDS
// latency), zero cross-lane ops, 14 dwordx4 + 6 dword loads per row issued
// BEFORE the prework so HBM latency hides under the knot-sort phase.
// ---------------------------------------------------------------------------
__global__ __launch_bounds__(256) void sfm_fused(
    const float* __restrict__ ego, const float* __restrict__ nei,
    const float* __restrict__ border, const float* __restrict__ adp,
    const float* __restrict__ eang,
    const float* __restrict__ an_wi, const float* __restrict__ an_bi,
    const float* __restrict__ an_wo, const float* __restrict__ an_bo,
    const float* __restrict__ rn_wi, const float* __restrict__ rn_bi,
    const float* __restrict__ rn_wo, const float* __restrict__ rn_bo,
    const float* __restrict__ rb_wi, const float* __restrict__ rb_bi,
    const float* __restrict__ rb_wo, const float* __restrict__ rb_bo,
    const float* __restrict__ dl_wi, const float* __restrict__ dl_bi,
    const float* __restrict__ dl_wo, const float* __restrict__ dl_bo,
    float* __restrict__ out, int Bn)
{
    // sw layout: [0..7] dlf | an@16, rn@128, rb@240 (knots/SufW/SufB) |
    //            [352..359] an_bo, rn_bo, rb_bo, adp0, adp1, ang, border0, border3
    __shared__ float sw[360];
    __shared__ float tk[96], w1[96], w2[96], sk[96], s1[96], s2[96];

    const int t = threadIdx.x;
    const int row = blockIdx.x * 256 + t;
    const int prow = (row < Bn) ? row : (Bn - 1);

    // ---- issue this row's loads FIRST (latency hides under prework) ----
    // nei row = 136 floats = 34 aligned float4 quads. Record l needs floats
    // 17l+2..17l+5, covered by quads (17l+2)>>2 and +1 with compile-time
    // component extraction.
    const float4* nq = (const float4*)(nei + (size_t)prow * 136);
    float4 a0 = nq[0],  b0 = nq[1];     // l=0: floats 2..5
    float4 a1 = nq[4],  b1 = nq[5];     // l=1: floats 19..22
    float4 a2 = nq[9];                  // l=2: floats 36..39 (one quad)
    float4 a3 = nq[13], b3 = nq[14];    // l=3: floats 53..56
    float4 a4 = nq[17], b4 = nq[18];    // l=4: floats 70..73
    float4 a5 = nq[21], b5 = nq[22];    // l=5: floats 87..90
    float4 a6 = nq[26];                 // l=6: floats 104..107 (one quad)
    float4 a7 = nq[30], b7 = nq[31];    // l=7: floats 121..124
    const float* er = ego + (size_t)prow * 51 + 34;
    float g0 = er[0], g1 = er[1], g2 = er[2], g3 = er[3], g4 = er[4], g5 = er[5];

    // --- pre-work, once per block ---
    if (t < 96) {
        int f = t >> 5, k = t & 31;
        const float* wip = (f == 0) ? an_wi : ((f == 1) ? rn_wi : rb_wi);
        const float* bip = (f == 0) ? an_bi : ((f == 1) ? rn_bi : rb_bi);
        const float* wop = (f == 0) ? an_wo : ((f == 1) ? rn_wo : rb_wo);
        float wi = wip[k], bi = bip[k], wo = wop[k];
        tk[t] = -bi / wi;
        w1[t] = wi * wo;
        w2[t] = wo * bi;
    }
    if (t >= 96 && t < 104) {                       // dlf[j], bo folded in
        int j = t - 96;
        const float* base = ego + 51;               // ego[1, :, :]
        float idv = base[2 * 17 + 8 + j];
        float dur = 0.f;
        for (int tt = 0; tt < 3; ++tt) {
            bool fo = false;
            for (int m = 0; m < 8; ++m) fo = fo || (idv == base[tt * 17 + 8 + m]);
            dur += fo ? 1.f : 0.f;
        }
        float acc = 0.f;
#pragma unroll
        for (int k = 0; k < 32; ++k)
            acc = fmaf(dl_wo[k], fmaxf(0.f, -fmaf(dl_wi[k], dur, dl_bi[k])), acc);
        sw[j] = acc + dl_bo[0];
    }
    if (t == 104) sw[352] = an_bo[0];
    if (t == 105) sw[353] = rn_bo[0];
    if (t == 106) sw[354] = rb_bo[0];
    if (t == 107) sw[355] = adp[0];
    if (t == 108) sw[356] = adp[1];
    if (t == 109) sw[357] = eang[0];
    if (t == 110) sw[358] = border[0];
    if (t == 111) sw[359] = border[3];
    __syncthreads();

    if (t < 96) {                                   // rank-sort the knots
        int k = t & 31, b = t & ~31;
        float my = tk[t];
        int rank = 0;
#pragma unroll
        for (int m = 0; m < 32; ++m) {
            float o = tk[b + m];
            rank += (o < my || (o == my && m < k)) ? 1 : 0;
        }
        sk[b + rank] = my;
        s1[b + rank] = w1[t];
        s2[b + rank] = w2[t];
    }
    __syncthreads();

    if (t < 96) {                                   // suffix sums (same order as ref)
        int f = t >> 5, p = t & 31, b = t & ~31;
        float sw_ = 0.f, sb_ = 0.f;
#pragma unroll
        for (int m = 0; m < 32; ++m) {
            float a = s1[b + m], c = s2[b + m];
            if (m >= p) { sw_ += a; sb_ += c; }
        }
        int base = 16 + f * 112;
        sw[base + p]      = sk[b + p];
        sw[base + 32 + p] = sw_;
        sw[base + 65 + p] = sb_;
        if (p == 0) { sw[base + 64] = 0.f; sw[base + 97] = 0.f; }
    }
    __syncthreads();

    // ---- main phase: whole row in this thread ----
    if (row < Bn) {
        const float an_bo_v = sw[352], rn_bo_v = sw[353], rb_bo_v = sw[354];
        const float p0 = sw[355], p1 = sw[356], ang = sw[357];
        float rb0 = g3 - sw[358], rb1 = g3 - sw[359];
        float rbn0 = fabsf(rb0), rbn1 = fabsf(rb1);

        // e = normalize(ego_last[4:6])
        float elen = sqrtf(g4 * g4 + g5 * g5);
        float ex = g4 / elen, ey = g5 / elen;
        float na = fmaxf(sqrtf(ex * ex + ey * ey), EPSC);

        float axs = 0.f, ays = 0.f;
#define CLAMP_ADD(VX, VY)                                                   \
        {                                                                   \
            float _vx = (VX), _vy = (VY);                                   \
            float _nv = fmaxf(sqrtf(_vx * _vx + _vy * _vy), EPSC);          \
            float _c = (ex * _vx + ey * _vy) / (na * _nv);                  \
            if (fabsf(_c) > ang) { axs += _vx; ays += _vy; }                \
        }

        // per-record: identical formulas to the verified 8-lane version;
        // inv_rr via 1-ulp v_rcp (smooth magnitude path only)
#define DO_REC(L, NX, NY, VX, VY)                                           \
        {                                                                   \
            float nx = (NX), ny = (NY), vx = (VX), vy = (VY);               \
            float Rx = nx - g2, Ry = ny - g3;                               \
            float rr = sqrtf(Rx * Rx + Ry * Ry);                            \
            float axq = fmaf(vx, DTC, Rx), ayq = fmaf(vy, DTC, Ry);         \
            float wxq = vx * DTC, wyq = vy * DTC;                           \
            float bb = sqrtf(rr + axq * axq + ayq * ayq                     \
                             - wxq * wxq - wyq * wyq) * 0.5f;               \
            float fA = mono_eval(sw + 16, rr) + an_bo_v;                    \
            float fR = mono_eval(sw + 128, bb) + rn_bo_v;                   \
            float inv_rr = __builtin_amdgcn_rcpf(rr);                       \
            float mfx = (nx == 0.f) ? 0.f : 1.f;                            \
            float mfy = (ny == 0.f) ? 0.f : 1.f;                            \
            float coefA = fA * inv_rr * sw[L];                              \
            CLAMP_ADD(coefA * Rx * mfx, coefA * Ry * mfy);                  \
            float coefR = fR * inv_rr;                                      \
            CLAMP_ADD(coefR * Rx * mfx, coefR * Ry * mfy);                  \
        }

        DO_REC(0, a0.z, a0.w, b0.x, b0.y);
        DO_REC(1, a1.w, b1.x, b1.y, b1.z);
        DO_REC(2, a2.x, a2.y, a2.z, a2.w);
        DO_REC(3, a3.y, a3.z, a3.w, b3.x);
        DO_REC(4, a4.z, a4.w, b4.x, b4.y);
        DO_REC(5, a5.w, b5.x, b5.y, b5.z);
        DO_REC(6, a6.x, a6.y, a6.z, a6.w);
        DO_REC(7, a7.y, a7.z, a7.w, b7.x);
#undef DO_REC

        // f_dest
        float dvn = sqrtf(g3 * g3 + g4 * g4);
        CLAMP_ADD((p1 * dvn - g3) / p0, -g4 / p0);
        // f_bor: (0, mono_rb(|rbv|) * sign(rbv)); rb/|rb| == ±1 exactly
        float vB0 = mono_eval(sw + 240, rbn0) + rb_bo_v;
        float vB1 = mono_eval(sw + 240, rbn1) + rb_bo_v;
        CLAMP_ADD(0.f, vB0 * copysignf(1.f, rb0));
        CLAMP_ADD(0.f, vB1 * copysignf(1.f, rb1));
#undef CLAMP_ADD

        float vxo = fmaf(axs, DTC, g2);
        float vyo = fmaf(ays, DTC, g3);
        float2* op = (float2*)(out + (size_t)row * 6);
        float2 o0; o0.x = fmaf(vxo, DTC, g0); o0.y = fmaf(vyo, DTC, g1);
        float2 o1; o1.x = vxo; o1.y = vyo;
        float2 o2; o2.x = axs; o2.y = ays;
        op[0] = o0; op[1] = o1; op[2] = o2;
    }
}

extern "C" void kernel_launch(void* const* d_in, const int* in_sizes, int n_in,
                              void* d_out, int out_size, void* d_ws, size_t ws_size,
                              hipStream_t stream) {
    const float* ego    = (const float*)d_in[0];
    const float* nei    = (const float*)d_in[1];
    const float* border = (const float*)d_in[2];
    const float* adp    = (const float*)d_in[3];
    const float* eang   = (const float*)d_in[4];
    const float* an_wi  = (const float*)d_in[5];
    const float* an_bi  = (const float*)d_in[6];
    const float* an_wo  = (const float*)d_in[7];
    const float* an_bo  = (const float*)d_in[8];
    const float* rn_wi  = (const float*)d_in[9];
    const float* rn_bi  = (const float*)d_in[10];
    const float* rn_wo  = (const float*)d_in[11];
    const float* rn_bo  = (const float*)d_in[12];
    const float* rb_wi  = (const float*)d_in[13];
    const float* rb_bi  = (const float*)d_in[14];
    const float* rb_wo  = (const float*)d_in[15];
    const float* rb_bo  = (const float*)d_in[16];
    const float* dl_wi  = (const float*)d_in[17];
    const float* dl_bi  = (const float*)d_in[18];
    const float* dl_wo  = (const float*)d_in[19];
    const float* dl_bo  = (const float*)d_in[20];
    float* out = (float*)d_out;
    (void)d_ws; (void)ws_size;                      // deliberately unused

    int Bn = in_sizes[0] / (3 * 17);
    int grid = (Bn + 255) / 256;
    sfm_fused<<<grid, 256, 0, stream>>>(ego, nei, border, adp, eang,
                                        an_wi, an_bi, an_wo, an_bo,
                                        rn_wi, rn_bi, rn_wo, rn_bo,
                                        rb_wi, rb_bi, rb_wo, rb_bo,
                                        dl_wi, dl_bi, dl_wo, dl_bo,
                                        out, Bn);
}